// Round 3
// baseline (807.078 us; speedup 1.0000x reference)
//
#include <hip/hip_runtime.h>
#include <hip/hip_bf16.h>

// ---------------- problem constants ----------------
constexpr int QKV  = 768;     // 3*8*32
constexpr int Nsp  = 16384;   // 16*32*32

// =====================================================================
// 1x1-conv GEMM:  Y[b][co][n] = sum_c W[co][c] * X[b][c][n]
// 128(co) x 128(n) tile, 8x8 micro-tile, K-chunks of 32.
// =====================================================================
__global__ __launch_bounds__(256)
void gemm1x1(const float* __restrict__ X, const float* __restrict__ W,
             float* __restrict__ Y, int K, int M)
{
    const int n0  = blockIdx.x * 128;
    const int co0 = blockIdx.y * 128;
    const int b   = blockIdx.z;
    const int t   = threadIdx.x;

    __shared__ float xs[32][128];
    __shared__ float wsh[32][128];

    const float* Xb = X + (size_t)b * K * Nsp;

    float acc[8][8];
#pragma unroll
    for (int i = 0; i < 8; i++)
#pragma unroll
        for (int j = 0; j < 8; j++) acc[i][j] = 0.f;

    const int tn = t & 15;   // n sub-index
    const int tc = t >> 4;   // co sub-index

    for (int k0 = 0; k0 < K; k0 += 32) {
        __syncthreads();
#pragma unroll
        for (int r = 0; r < 4; r++) {
            int id  = t + 256 * r;
            int row = id >> 5;          // 0..31
            int q   = id & 31;
            float4 v = *reinterpret_cast<const float4*>(
                Xb + (size_t)(k0 + row) * Nsp + n0 + q * 4);
            *reinterpret_cast<float4*>(&xs[row][q * 4]) = v;
        }
#pragma unroll
        for (int r = 0; r < 4; r++) {
            int id  = t + 256 * r;
            int coi = id >> 3;          // 0..127
            int cq  = id & 7;
            float4 v = *reinterpret_cast<const float4*>(
                W + (size_t)(co0 + coi) * K + k0 + cq * 4);
            wsh[cq * 4 + 0][coi] = v.x;
            wsh[cq * 4 + 1][coi] = v.y;
            wsh[cq * 4 + 2][coi] = v.z;
            wsh[cq * 4 + 3][coi] = v.w;
        }
        __syncthreads();
#pragma unroll 8
        for (int kk = 0; kk < 32; kk++) {
            float4 xa = *reinterpret_cast<const float4*>(&xs[kk][tn * 4]);
            float4 xb = *reinterpret_cast<const float4*>(&xs[kk][64 + tn * 4]);
            float4 wa = *reinterpret_cast<const float4*>(&wsh[kk][tc * 4]);
            float4 wb = *reinterpret_cast<const float4*>(&wsh[kk][64 + tc * 4]);
            float xr[8] = {xa.x, xa.y, xa.z, xa.w, xb.x, xb.y, xb.z, xb.w};
            float wr[8] = {wa.x, wa.y, wa.z, wa.w, wb.x, wb.y, wb.z, wb.w};
#pragma unroll
            for (int i = 0; i < 8; i++)
#pragma unroll
                for (int j = 0; j < 8; j++)
                    acc[i][j] = fmaf(wr[i], xr[j], acc[i][j]);
        }
    }

#pragma unroll
    for (int g = 0; g < 2; g++) {
#pragma unroll
        for (int j = 0; j < 4; j++) {
            int i  = g * 4 + j;
            int co = co0 + g * 64 + tc * 4 + j;
            float* yp = Y + ((size_t)b * M + co) * Nsp + n0;
            *reinterpret_cast<float4*>(yp + tn * 4) =
                make_float4(acc[i][0], acc[i][1], acc[i][2], acc[i][3]);
            *reinterpret_cast<float4*>(yp + 64 + tn * 4) =
                make_float4(acc[i][4], acc[i][5], acc[i][6], acc[i][7]);
        }
    }
}

// =====================================================================
// Depthwise 5x5x5 conv, pad 2, SINGLE batch. One block = (ch, 4 d-planes).
// =====================================================================
__global__ __launch_bounds__(256)
void dwconv5(const float* __restrict__ X, const float* __restrict__ Wd,
             float* __restrict__ Y)
{
    const int dt = blockIdx.x;      // 0..3
    const int ch = blockIdx.y;      // 0..767
    const int d0 = dt * 4;
    const int t  = threadIdx.x;

    __shared__ float s[8][36][38];

    const float* Xc = X + (size_t)ch * Nsp;
    for (int idx = t; idx < 8 * 36 * 36; idx += 256) {
        int dd  = idx / 1296;
        int rem = idx - dd * 1296;
        int hh  = rem / 36;
        int ww  = rem - hh * 36;
        int d = d0 + dd - 2, h = hh - 2, w = ww - 2;
        float v = 0.f;
        if (d >= 0 && d < 16 && h >= 0 && h < 32 && w >= 0 && w < 32)
            v = Xc[(d * 32 + h) * 32 + w];
        s[dd][hh][ww] = v;
    }
    __syncthreads();

    const float* wp = Wd + ch * 125;
    const int h  = t >> 3;
    const int w4 = (t & 7) * 4;
    float* Yc = Y + (size_t)ch * Nsp;

#pragma unroll
    for (int d = 0; d < 4; d++) {
        float a0 = 0, a1 = 0, a2 = 0, a3 = 0;
#pragma unroll
        for (int kd = 0; kd < 5; kd++) {
#pragma unroll
            for (int kh = 0; kh < 5; kh++) {
                const float* row = &s[d + kd][h + kh][w4];
                float2 r01 = *reinterpret_cast<const float2*>(row);
                float2 r23 = *reinterpret_cast<const float2*>(row + 2);
                float2 r45 = *reinterpret_cast<const float2*>(row + 4);
                float2 r67 = *reinterpret_cast<const float2*>(row + 6);
                float r[8] = {r01.x, r01.y, r23.x, r23.y, r45.x, r45.y, r67.x, r67.y};
#pragma unroll
                for (int kw = 0; kw < 5; kw++) {
                    float wv = wp[(kd * 5 + kh) * 5 + kw];
                    a0 = fmaf(wv, r[kw + 0], a0);
                    a1 = fmaf(wv, r[kw + 1], a1);
                    a2 = fmaf(wv, r[kw + 2], a2);
                    a3 = fmaf(wv, r[kw + 3], a3);
                }
            }
        }
        *reinterpret_cast<float4*>(Yc + ((d0 + d) * 32 + h) * 32 + w4)
            = make_float4(a0, a1, a2, a3);
    }
}

// =====================================================================
// Grouped pointwise conv (single batch): 24 groups of 32->32 channels.
// =====================================================================
__global__ __launch_bounds__(256)
void pwconv(const float* __restrict__ X, const float* __restrict__ Wp,
            float* __restrict__ Y)
{
    const int n0 = blockIdx.x * 256;
    const int g  = blockIdx.y;      // 0..23
    const int t  = threadIdx.x;
    const int lane = t & 63, wv = t >> 6;

    __shared__ float xs[32][256];

    const float* Xg = X + (size_t)(g * 32) * Nsp + n0;
#pragma unroll
    for (int rr = 0; rr < 8; rr++) {
        int r = wv + rr * 4;
        float4 v = *reinterpret_cast<const float4*>(Xg + (size_t)r * Nsp + lane * 4);
        *reinterpret_cast<float4*>(&xs[r][lane * 4]) = v;
    }
    __syncthreads();

    float xin[32];
#pragma unroll
    for (int j = 0; j < 32; j++) xin[j] = xs[j][t];

    const float* wg = Wp + g * 1024;
    float* Yg = Y + (size_t)(g * 32) * Nsp + n0;
#pragma unroll 4
    for (int co = 0; co < 32; co++) {
        float acc = 0;
#pragma unroll
        for (int j = 0; j < 32; j++) acc = fmaf(wg[co * 32 + j], xin[j], acc);
        Yg[(size_t)co * Nsp + t] = acc;
    }
}

// =====================================================================
// Attention phase 1: vk[e][d] partials, 16 chunks x 1024 n each.
// e in 0..32 (row 32 = ones row -> k column sums), d in 0..31.
// =====================================================================
__global__ __launch_bounds__(256)
void att_vk(const float* __restrict__ QKVb, const float* __restrict__ AGG2,
            float* __restrict__ vk_part)
{
    const int chunk = blockIdx.x;   // 0..15
    const int bh    = blockIdx.y;   // 0..31
    const int b = bh >> 4, head = bh & 15;
    const float* base = (head < 8)
        ? QKVb + ((size_t)b * QKV + head * 96) * Nsp
        : AGG2 + ((size_t)b * QKV + (head - 8) * 96) * Nsp;

    __shared__ float ks[32][256];
    __shared__ float vs[32][256];

    const int t = threadIdx.x;
    const int lane = t & 63, wv = t >> 6;
    const int a  = t & 15;
    const int e0 = t >> 4;          // 0..15
    const int d0 = 2 * a;
    const int rot = (2 * d0 + 34 * e0) & 255;   // even -> float2 aligned

    float a00 = 0, a01 = 0, a10 = 0, a11 = 0, s0 = 0, s1 = 0;

    for (int sub = 0; sub < 4; sub++) {
        const int n0 = chunk * 1024 + sub * 256;
        __syncthreads();
#pragma unroll
        for (int rr = 0; rr < 16; rr++) {
            int rid = wv + rr * 4;      // 0..63
            if (rid < 32) {
                float4 v = *reinterpret_cast<const float4*>(
                    base + (size_t)(32 + rid) * Nsp + n0 + lane * 4);
                v.x = fmaxf(v.x, 0.f); v.y = fmaxf(v.y, 0.f);
                v.z = fmaxf(v.z, 0.f); v.w = fmaxf(v.w, 0.f);
                *reinterpret_cast<float4*>(&ks[rid][lane * 4]) = v;
            } else {
                float4 v = *reinterpret_cast<const float4*>(
                    base + (size_t)(64 + rid - 32) * Nsp + n0 + lane * 4);
                *reinterpret_cast<float4*>(&vs[rid - 32][lane * 4]) = v;
            }
        }
        __syncthreads();

#pragma unroll 4
        for (int n = 0; n < 256; n += 2) {
            int nn = (n + rot) & 255;
            float2 k0 = *reinterpret_cast<const float2*>(&ks[d0][nn]);
            float2 k1 = *reinterpret_cast<const float2*>(&ks[d0 + 1][nn]);
            float2 v0 = *reinterpret_cast<const float2*>(&vs[e0][nn]);
            float2 v1 = *reinterpret_cast<const float2*>(&vs[e0 + 16][nn]);
            a00 = fmaf(v0.x, k0.x, fmaf(v0.y, k0.y, a00));
            a01 = fmaf(v0.x, k1.x, fmaf(v0.y, k1.y, a01));
            a10 = fmaf(v1.x, k0.x, fmaf(v1.y, k0.y, a10));
            a11 = fmaf(v1.x, k1.x, fmaf(v1.y, k1.y, a11));
            s0 += k0.x + k0.y;
            s1 += k1.x + k1.y;
        }
    }

    float* vp = vk_part + ((size_t)bh * 16 + chunk) * 1056;
    vp[e0 * 32 + d0]            = a00;
    vp[e0 * 32 + d0 + 1]        = a01;
    vp[(e0 + 16) * 32 + d0]     = a10;
    vp[(e0 + 16) * 32 + d0 + 1] = a11;
    if (e0 == 0) {
        vp[32 * 32 + d0]     = s0;
        vp[32 * 32 + d0 + 1] = s1;
    }
}

// Reduce the 16 chunk partials -> vk[bh][33][32]
__global__ __launch_bounds__(256)
void att_vk_reduce(const float* __restrict__ vk_part, float* __restrict__ vk)
{
    const int bh = blockIdx.x;
    const int t  = threadIdx.x;
    for (int id = t; id < 1056; id += 256) {
        const float* p = vk_part + (size_t)bh * 16 * 1056 + id;
        float s = 0;
#pragma unroll
        for (int c = 0; c < 16; c++) s += p[(size_t)c * 1056];
        vk[bh * 1056 + id] = s;
    }
}

// =====================================================================
// M'[b][co][h*32+d] = sum_e w_proj[co][h*32+e] * vk[b*16+h][e][d]
// =====================================================================
__global__ __launch_bounds__(256)
void mprep(const float* __restrict__ Wproj, const float* __restrict__ vk,
           float* __restrict__ Mp)
{
    const int b   = blockIdx.y;
    const int co0 = blockIdx.x * 16;
    const int t   = threadIdx.x;
    for (int ci = 0; ci < 16; ci++) {
        int co = co0 + ci;
        for (int hd = t; hd < 512; hd += 256) {
            int h = hd >> 5, d = hd & 31;
            const float* wrow = Wproj + (size_t)co * 512 + h * 32;
            const float* vkb  = vk + (size_t)(b * 16 + h) * 1056 + d;
            float s = 0;
#pragma unroll
            for (int e = 0; e < 32; e++) s = fmaf(wrow[e], vkb[e * 32], s);
            Mp[((size_t)b * 256 + co) * 512 + hd] = s;
        }
    }
}

// =====================================================================
// rden[bh][n] = 1 / (sum_d vk[bh][32][d] * relu(q[d][n]) + 1e-15)
// =====================================================================
__global__ __launch_bounds__(256)
void rden_k(const float* __restrict__ QKVb, const float* __restrict__ AGG2,
            const float* __restrict__ vk, float* __restrict__ Rden)
{
    const int n0 = blockIdx.x * 256;
    const int bh = blockIdx.y;
    const int b = bh >> 4, head = bh & 15;
    const float* base = (head < 8)
        ? QKVb + ((size_t)b * QKV + head * 96) * Nsp
        : AGG2 + ((size_t)b * QKV + (head - 8) * 96) * Nsp;
    const float* vk1 = vk + (size_t)bh * 1056 + 1024;
    const int t = threadIdx.x;
    float acc = 0;
#pragma unroll
    for (int d = 0; d < 32; d++)
        acc = fmaf(vk1[d], fmaxf(base[(size_t)d * Nsp + n0 + t], 0.f), acc);
    Rden[(size_t)bh * Nsp + n0 + t] = 1.0f / (acc + 1e-15f);
}

// =====================================================================
// Fused attention-out + proj + BN:
//   out[b][co][n] = BN( sum_{hd} Mp[b][co][hd] * relu(q[h,d,n])*rden[bh][n] )
// K-chunk k0 covers hd = k0..k0+31 -> h = k0/32 constant per chunk.
// =====================================================================
__global__ __launch_bounds__(256)
void gemm_proj(const float* __restrict__ QKVb, const float* __restrict__ AGG2,
               const float* __restrict__ Mp, const float* __restrict__ Rden,
               float* __restrict__ Y,
               const float* __restrict__ gamma, const float* __restrict__ beta,
               const float* __restrict__ rmean, const float* __restrict__ rvar)
{
    const int n0  = blockIdx.x * 128;
    const int co0 = blockIdx.y * 128;
    const int b   = blockIdx.z;
    const int t   = threadIdx.x;

    __shared__ float xs[32][128];
    __shared__ float wsh[32][128];

    float acc[8][8];
#pragma unroll
    for (int i = 0; i < 8; i++)
#pragma unroll
        for (int j = 0; j < 8; j++) acc[i][j] = 0.f;

    const int tn = t & 15;
    const int tc = t >> 4;
    const float* Wb = Mp + (size_t)b * 256 * 512;

    for (int k0 = 0; k0 < 512; k0 += 32) {
        const int h = k0 >> 5;                  // 0..15
        const float* qbase = (h < 8)
            ? QKVb + ((size_t)b * QKV + h * 96) * Nsp
            : AGG2 + ((size_t)b * QKV + (h - 8) * 96) * Nsp;
        const float* rd = Rden + (size_t)(b * 16 + h) * Nsp + n0;

        __syncthreads();
#pragma unroll
        for (int r = 0; r < 4; r++) {
            int id  = t + 256 * r;
            int row = id >> 5;                  // d = 0..31
            int q   = id & 31;
            float4 v = *reinterpret_cast<const float4*>(
                qbase + (size_t)row * Nsp + n0 + q * 4);
            float4 s = *reinterpret_cast<const float4*>(rd + q * 4);
            v.x = fmaxf(v.x, 0.f) * s.x;
            v.y = fmaxf(v.y, 0.f) * s.y;
            v.z = fmaxf(v.z, 0.f) * s.z;
            v.w = fmaxf(v.w, 0.f) * s.w;
            *reinterpret_cast<float4*>(&xs[row][q * 4]) = v;
        }
#pragma unroll
        for (int r = 0; r < 4; r++) {
            int id  = t + 256 * r;
            int coi = id >> 3;
            int cq  = id & 7;
            float4 v = *reinterpret_cast<const float4*>(
                Wb + (size_t)(co0 + coi) * 512 + k0 + cq * 4);
            wsh[cq * 4 + 0][coi] = v.x;
            wsh[cq * 4 + 1][coi] = v.y;
            wsh[cq * 4 + 2][coi] = v.z;
            wsh[cq * 4 + 3][coi] = v.w;
        }
        __syncthreads();
#pragma unroll 8
        for (int kk = 0; kk < 32; kk++) {
            float4 xa = *reinterpret_cast<const float4*>(&xs[kk][tn * 4]);
            float4 xb = *reinterpret_cast<const float4*>(&xs[kk][64 + tn * 4]);
            float4 wa = *reinterpret_cast<const float4*>(&wsh[kk][tc * 4]);
            float4 wb = *reinterpret_cast<const float4*>(&wsh[kk][64 + tc * 4]);
            float xr[8] = {xa.x, xa.y, xa.z, xa.w, xb.x, xb.y, xb.z, xb.w};
            float wr[8] = {wa.x, wa.y, wa.z, wa.w, wb.x, wb.y, wb.z, wb.w};
#pragma unroll
            for (int i = 0; i < 8; i++)
#pragma unroll
                for (int j = 0; j < 8; j++)
                    acc[i][j] = fmaf(wr[i], xr[j], acc[i][j]);
        }
    }

#pragma unroll
    for (int g = 0; g < 2; g++) {
#pragma unroll
        for (int j = 0; j < 4; j++) {
            int i  = g * 4 + j;
            int co = co0 + g * 64 + tc * 4 + j;
            float rs = rsqrtf(rvar[co] + 1e-5f);
            float sc = gamma[co] * rs;
            float sh = beta[co] - rmean[co] * sc;
            float* yp = Y + ((size_t)b * 256 + co) * Nsp + n0;
            float4 o0 = make_float4(fmaf(acc[i][0], sc, sh), fmaf(acc[i][1], sc, sh),
                                    fmaf(acc[i][2], sc, sh), fmaf(acc[i][3], sc, sh));
            float4 o1 = make_float4(fmaf(acc[i][4], sc, sh), fmaf(acc[i][5], sc, sh),
                                    fmaf(acc[i][6], sc, sh), fmaf(acc[i][7], sc, sh));
            *reinterpret_cast<float4*>(yp + tn * 4)      = o0;
            *reinterpret_cast<float4*>(yp + 64 + tn * 4) = o1;
        }
    }
}

// =====================================================================
extern "C" void kernel_launch(void* const* d_in, const int* in_sizes, int n_in,
                              void* d_out, int out_size, void* d_ws, size_t ws_size,
                              hipStream_t stream)
{
    const float* x      = (const float*)d_in[0];
    const float* w_qkv  = (const float*)d_in[1];
    const float* w_dw   = (const float*)d_in[2];
    const float* w_pw   = (const float*)d_in[3];
    const float* w_proj = (const float*)d_in[4];
    const float* gamma  = (const float*)d_in[5];
    const float* beta   = (const float*)d_in[6];
    const float* rmean  = (const float*)d_in[7];
    const float* rvar   = (const float*)d_in[8];
    float* out = (float*)d_out;

    const size_t SZf = (size_t)2 * QKV * Nsp;    // floats in full 2-batch buffer
    const size_t HBf = (size_t)QKV * Nsp;        // floats in 1-batch buffer
    float* qkv  = (float*)d_ws;                  // [0, SZf)
    float* agg2 = qkv + SZf;                     // [SZf, 2*SZf)
    float* aggH = agg2 + SZf;                    // [2*SZf, 2*SZf + HBf)  per-batch dw out
    // overlay region (aggH dead after pwconv(b=1)):
    float* vkp  = aggH;                          // 32*16*1056
    float* vkf  = vkp + (size_t)32 * 16 * 1056;  // 32*1056
    float* rden = vkf + (size_t)32 * 1056;       // 32*16384
    float* Mp   = rden + (size_t)32 * 16384;     // 2*256*512
    // peak = 2*SZf + HBf floats = 240 MiB

    dim3 blk(256);
    // 1) qkv = conv1x1(x)
    gemm1x1<<<dim3(128, 6, 2), blk, 0, stream>>>(x, w_qkv, qkv, 256, 768);
    // 2+3) per-batch: depthwise 5^3 -> half buffer, grouped pointwise -> agg2
    for (int b = 0; b < 2; b++) {
        dwconv5<<<dim3(4, 768), blk, 0, stream>>>(qkv + (size_t)b * HBf, w_dw, aggH);
        pwconv<<<dim3(64, 24), blk, 0, stream>>>(aggH, w_pw, agg2 + (size_t)b * HBf);
    }
    // 4) vk partials + reduce (safe to overlay aggH: stream-ordered after pwconv)
    att_vk<<<dim3(16, 32), blk, 0, stream>>>(qkv, agg2, vkp);
    att_vk_reduce<<<dim3(32), blk, 0, stream>>>(vkp, vkf);
    // 5) M' = w_proj (x) vk  and  rden
    mprep<<<dim3(16, 2), blk, 0, stream>>>(w_proj, vkf, Mp);
    rden_k<<<dim3(64, 32), blk, 0, stream>>>(qkv, agg2, vkf, rden);
    // 6) fused attention-out + proj + BN
    gemm_proj<<<dim3(128, 2, 2), blk, 0, stream>>>(
        qkv, agg2, Mp, rden, out, gamma, beta, rmean, rvar);
}

// Round 4
// 588.132 us; speedup vs baseline: 1.3723x; 1.3723x over previous
//
#include <hip/hip_runtime.h>
#include <hip/hip_bf16.h>

// ---------------- problem constants ----------------
constexpr int QKV  = 768;     // 3*8*32
constexpr int Nsp  = 16384;   // 16*32*32

// =====================================================================
// 1x1-conv GEMM:  Y[b][co][n] = sum_c W[co][c] * X[b][c][n]
// 128(co) x 128(n) tile, 8x8 micro-tile, K-chunks of 32.
// =====================================================================
__global__ __launch_bounds__(256)
void gemm1x1(const float* __restrict__ X, const float* __restrict__ W,
             float* __restrict__ Y, int K, int M)
{
    const int n0  = blockIdx.x * 128;
    const int co0 = blockIdx.y * 128;
    const int b   = blockIdx.z;
    const int t   = threadIdx.x;

    __shared__ float xs[32][128];
    __shared__ float wsh[32][128];

    const float* Xb = X + (size_t)b * K * Nsp;

    float acc[8][8];
#pragma unroll
    for (int i = 0; i < 8; i++)
#pragma unroll
        for (int j = 0; j < 8; j++) acc[i][j] = 0.f;

    const int tn = t & 15;   // n sub-index
    const int tc = t >> 4;   // co sub-index

    for (int k0 = 0; k0 < K; k0 += 32) {
        __syncthreads();
#pragma unroll
        for (int r = 0; r < 4; r++) {
            int id  = t + 256 * r;
            int row = id >> 5;          // 0..31
            int q   = id & 31;
            float4 v = *reinterpret_cast<const float4*>(
                Xb + (size_t)(k0 + row) * Nsp + n0 + q * 4);
            *reinterpret_cast<float4*>(&xs[row][q * 4]) = v;
        }
#pragma unroll
        for (int r = 0; r < 4; r++) {
            int id  = t + 256 * r;
            int coi = id >> 3;          // 0..127
            int cq  = id & 7;
            float4 v = *reinterpret_cast<const float4*>(
                W + (size_t)(co0 + coi) * K + k0 + cq * 4);
            wsh[cq * 4 + 0][coi] = v.x;
            wsh[cq * 4 + 1][coi] = v.y;
            wsh[cq * 4 + 2][coi] = v.z;
            wsh[cq * 4 + 3][coi] = v.w;
        }
        __syncthreads();
#pragma unroll 8
        for (int kk = 0; kk < 32; kk++) {
            float4 xa = *reinterpret_cast<const float4*>(&xs[kk][tn * 4]);
            float4 xb = *reinterpret_cast<const float4*>(&xs[kk][64 + tn * 4]);
            float4 wa = *reinterpret_cast<const float4*>(&wsh[kk][tc * 4]);
            float4 wb = *reinterpret_cast<const float4*>(&wsh[kk][64 + tc * 4]);
            float xr[8] = {xa.x, xa.y, xa.z, xa.w, xb.x, xb.y, xb.z, xb.w};
            float wr[8] = {wa.x, wa.y, wa.z, wa.w, wb.x, wb.y, wb.z, wb.w};
#pragma unroll
            for (int i = 0; i < 8; i++)
#pragma unroll
                for (int j = 0; j < 8; j++)
                    acc[i][j] = fmaf(wr[i], xr[j], acc[i][j]);
        }
    }

#pragma unroll
    for (int g = 0; g < 2; g++) {
#pragma unroll
        for (int j = 0; j < 4; j++) {
            int i  = g * 4 + j;
            int co = co0 + g * 64 + tc * 4 + j;
            float* yp = Y + ((size_t)b * M + co) * Nsp + n0;
            *reinterpret_cast<float4*>(yp + tn * 4) =
                make_float4(acc[i][0], acc[i][1], acc[i][2], acc[i][3]);
            *reinterpret_cast<float4*>(yp + 64 + tn * 4) =
                make_float4(acc[i][4], acc[i][5], acc[i][6], acc[i][7]);
        }
    }
}

// =====================================================================
// Depthwise 5x5x5 conv, pad 2, SINGLE batch — plane-streaming version.
// One block = one channel. 16 D-planes stream through a double-buffered
// LDS plane (stride 40 -> <=2-way bank aliasing = free). Each input
// plane scatters into 5 register accumulator planes (ring, static idx).
// 125 weights in registers, loaded once. Halo frame zeroed once.
// =====================================================================
#define FMA4(A, WV, R, K)                \
    A.x = fmaf(WV, R[K + 0], A.x);       \
    A.y = fmaf(WV, R[K + 1], A.y);       \
    A.z = fmaf(WV, R[K + 2], A.z);       \
    A.w = fmaf(WV, R[K + 3], A.w);

// slot a_j holds output plane d = z+2-j at entry; gets weight slice kd=j.
#define PLANE_STEP(Z, G0, G1, G2, G3, G4, DOWRITE, DOSTAGE)                   \
  {                                                                           \
    const int zz  = (Z);                                                      \
    const int cur = zz & 1;                                                   \
    __syncthreads();                                                          \
    float4 g = {0.f, 0.f, 0.f, 0.f};                                          \
    if (DOSTAGE)                                                              \
      g = *reinterpret_cast<const float4*>(Xc + (zz + 1) * 1024 +             \
                                           hrow * 32 + w4);                   \
    _Pragma("unroll")                                                         \
    for (int kh = 0; kh < 5; kh++) {                                          \
      const float* rp = &pl[cur][hrow + kh][w4];                              \
      float4 c0 = *reinterpret_cast<const float4*>(rp);                       \
      float4 c1 = *reinterpret_cast<const float4*>(rp + 4);                   \
      float r[8] = {c0.x, c0.y, c0.z, c0.w, c1.x, c1.y, c1.z, c1.w};          \
      _Pragma("unroll")                                                       \
      for (int kw = 0; kw < 5; kw++) {                                        \
        if (G0) { float wv = wr[  0 + kh * 5 + kw]; FMA4(a0, wv, r, kw) }     \
        if (G1) { float wv = wr[ 25 + kh * 5 + kw]; FMA4(a1, wv, r, kw) }     \
        if (G2) { float wv = wr[ 50 + kh * 5 + kw]; FMA4(a2, wv, r, kw) }     \
        if (G3) { float wv = wr[ 75 + kh * 5 + kw]; FMA4(a3, wv, r, kw) }     \
        if (G4) { float wv = wr[100 + kh * 5 + kw]; FMA4(a4, wv, r, kw) }     \
      }                                                                       \
    }                                                                         \
    if (DOWRITE)                                                              \
      *reinterpret_cast<float4*>(Yc + ((zz - 2) * 32 + hrow) * 32 + w4) = a4; \
    a4 = a3; a3 = a2; a2 = a1; a1 = a0;                                       \
    a0.x = 0.f; a0.y = 0.f; a0.z = 0.f; a0.w = 0.f;                           \
    if (DOSTAGE) {                                                            \
      const int nxt = cur ^ 1;                                                \
      pl[nxt][hrow + 2][2 + w4 + 0] = g.x;                                    \
      pl[nxt][hrow + 2][2 + w4 + 1] = g.y;                                    \
      pl[nxt][hrow + 2][2 + w4 + 2] = g.z;                                    \
      pl[nxt][hrow + 2][2 + w4 + 3] = g.w;                                    \
    }                                                                         \
  }

__global__ __launch_bounds__(256)
void dwconv5(const float* __restrict__ X, const float* __restrict__ Wd,
             float* __restrict__ Y)
{
    const int ch = blockIdx.x;      // 0..767
    const int t  = threadIdx.x;

    __shared__ float pl[2][36][40]; // 11.5 KB, halo frame permanently 0

    const float* Xc = X + (size_t)ch * Nsp;
    float*       Yc = Y + (size_t)ch * Nsp;
    const float* wp = Wd + ch * 125;

    float wr[125];
#pragma unroll
    for (int i = 0; i < 125; i++) wr[i] = wp[i];

    // zero both buffers once (h/w halo is constant across planes)
    for (int i = t; i < 2 * 36 * 40; i += 256)
        (&pl[0][0][0])[i] = 0.f;

    const int hrow = t >> 3;        // 0..31 : output row / staging row
    const int w4   = (t & 7) * 4;   // output col base; LDS col = w+2

    __syncthreads();                // zero-init before plane-0 staging
    {
        float4 g = *reinterpret_cast<const float4*>(Xc + hrow * 32 + w4);
        pl[0][hrow + 2][2 + w4 + 0] = g.x;
        pl[0][hrow + 2][2 + w4 + 1] = g.y;
        pl[0][hrow + 2][2 + w4 + 2] = g.z;
        pl[0][hrow + 2][2 + w4 + 3] = g.w;
    }

    float4 a0 = {0,0,0,0}, a1 = a0, a2 = a0, a3 = a0, a4 = a0;

    PLANE_STEP(0, true, true, true, false, false, false, true)
    PLANE_STEP(1, true, true, true, true,  false, false, true)
#pragma unroll 1
    for (int z = 2; z <= 13; z++) {
        PLANE_STEP(z, true, true, true, true, true, true, true)
    }
    PLANE_STEP(14, false, true,  true, true, true, true, true)
    PLANE_STEP(15, false, false, true, true, true, true, false)
    // after z=15 rotation: a4 = plane 14, a3 = plane 15
    *reinterpret_cast<float4*>(Yc + ((14 * 32 + hrow) * 32 + w4)) = a4;
    *reinterpret_cast<float4*>(Yc + ((15 * 32 + hrow) * 32 + w4)) = a3;
}

// =====================================================================
// Grouped pointwise conv (single batch): 24 groups of 32->32 channels.
// =====================================================================
__global__ __launch_bounds__(256)
void pwconv(const float* __restrict__ X, const float* __restrict__ Wp,
            float* __restrict__ Y)
{
    const int n0 = blockIdx.x * 256;
    const int g  = blockIdx.y;      // 0..23
    const int t  = threadIdx.x;
    const int lane = t & 63, wv = t >> 6;

    __shared__ float xs[32][256];

    const float* Xg = X + (size_t)(g * 32) * Nsp + n0;
#pragma unroll
    for (int rr = 0; rr < 8; rr++) {
        int r = wv + rr * 4;
        float4 v = *reinterpret_cast<const float4*>(Xg + (size_t)r * Nsp + lane * 4);
        *reinterpret_cast<float4*>(&xs[r][lane * 4]) = v;
    }
    __syncthreads();

    float xin[32];
#pragma unroll
    for (int j = 0; j < 32; j++) xin[j] = xs[j][t];

    const float* wg = Wp + g * 1024;
    float* Yg = Y + (size_t)(g * 32) * Nsp + n0;
#pragma unroll 4
    for (int co = 0; co < 32; co++) {
        float acc = 0;
#pragma unroll
        for (int j = 0; j < 32; j++) acc = fmaf(wg[co * 32 + j], xin[j], acc);
        Yg[(size_t)co * Nsp + t] = acc;
    }
}

// =====================================================================
// Attention phase 1: vk[e][d] partials, 16 chunks x 1024 n each.
// e in 0..32 (row 32 = ones row -> k column sums), d in 0..31.
// =====================================================================
__global__ __launch_bounds__(256)
void att_vk(const float* __restrict__ QKVb, const float* __restrict__ AGG2,
            float* __restrict__ vk_part)
{
    const int chunk = blockIdx.x;   // 0..15
    const int bh    = blockIdx.y;   // 0..31
    const int b = bh >> 4, head = bh & 15;
    const float* base = (head < 8)
        ? QKVb + ((size_t)b * QKV + head * 96) * Nsp
        : AGG2 + ((size_t)b * QKV + (head - 8) * 96) * Nsp;

    __shared__ float ks[32][256];
    __shared__ float vs[32][256];

    const int t = threadIdx.x;
    const int lane = t & 63, wv = t >> 6;
    const int a  = t & 15;
    const int e0 = t >> 4;          // 0..15
    const int d0 = 2 * a;
    const int rot = (2 * d0 + 34 * e0) & 255;   // even -> float2 aligned

    float a00 = 0, a01 = 0, a10 = 0, a11 = 0, s0 = 0, s1 = 0;

    for (int sub = 0; sub < 4; sub++) {
        const int n0 = chunk * 1024 + sub * 256;
        __syncthreads();
#pragma unroll
        for (int rr = 0; rr < 16; rr++) {
            int rid = wv + rr * 4;      // 0..63
            if (rid < 32) {
                float4 v = *reinterpret_cast<const float4*>(
                    base + (size_t)(32 + rid) * Nsp + n0 + lane * 4);
                v.x = fmaxf(v.x, 0.f); v.y = fmaxf(v.y, 0.f);
                v.z = fmaxf(v.z, 0.f); v.w = fmaxf(v.w, 0.f);
                *reinterpret_cast<float4*>(&ks[rid][lane * 4]) = v;
            } else {
                float4 v = *reinterpret_cast<const float4*>(
                    base + (size_t)(64 + rid - 32) * Nsp + n0 + lane * 4);
                *reinterpret_cast<float4*>(&vs[rid - 32][lane * 4]) = v;
            }
        }
        __syncthreads();

#pragma unroll 4
        for (int n = 0; n < 256; n += 2) {
            int nn = (n + rot) & 255;
            float2 k0 = *reinterpret_cast<const float2*>(&ks[d0][nn]);
            float2 k1 = *reinterpret_cast<const float2*>(&ks[d0 + 1][nn]);
            float2 v0 = *reinterpret_cast<const float2*>(&vs[e0][nn]);
            float2 v1 = *reinterpret_cast<const float2*>(&vs[e0 + 16][nn]);
            a00 = fmaf(v0.x, k0.x, fmaf(v0.y, k0.y, a00));
            a01 = fmaf(v0.x, k1.x, fmaf(v0.y, k1.y, a01));
            a10 = fmaf(v1.x, k0.x, fmaf(v1.y, k0.y, a10));
            a11 = fmaf(v1.x, k1.x, fmaf(v1.y, k1.y, a11));
            s0 += k0.x + k0.y;
            s1 += k1.x + k1.y;
        }
    }

    float* vp = vk_part + ((size_t)bh * 16 + chunk) * 1056;
    vp[e0 * 32 + d0]            = a00;
    vp[e0 * 32 + d0 + 1]        = a01;
    vp[(e0 + 16) * 32 + d0]     = a10;
    vp[(e0 + 16) * 32 + d0 + 1] = a11;
    if (e0 == 0) {
        vp[32 * 32 + d0]     = s0;
        vp[32 * 32 + d0 + 1] = s1;
    }
}

// Reduce the 16 chunk partials -> vk[bh][33][32]
__global__ __launch_bounds__(256)
void att_vk_reduce(const float* __restrict__ vk_part, float* __restrict__ vk)
{
    const int bh = blockIdx.x;
    const int t  = threadIdx.x;
    for (int id = t; id < 1056; id += 256) {
        const float* p = vk_part + (size_t)bh * 16 * 1056 + id;
        float s = 0;
#pragma unroll
        for (int c = 0; c < 16; c++) s += p[(size_t)c * 1056];
        vk[bh * 1056 + id] = s;
    }
}

// =====================================================================
// M'[b][co][h*32+d] = sum_e w_proj[co][h*32+e] * vk[b*16+h][e][d]
// =====================================================================
__global__ __launch_bounds__(256)
void mprep(const float* __restrict__ Wproj, const float* __restrict__ vk,
           float* __restrict__ Mp)
{
    const int b   = blockIdx.y;
    const int co0 = blockIdx.x * 16;
    const int t   = threadIdx.x;
    for (int ci = 0; ci < 16; ci++) {
        int co = co0 + ci;
        for (int hd = t; hd < 512; hd += 256) {
            int h = hd >> 5, d = hd & 31;
            const float* wrow = Wproj + (size_t)co * 512 + h * 32;
            const float* vkb  = vk + (size_t)(b * 16 + h) * 1056 + d;
            float s = 0;
#pragma unroll
            for (int e = 0; e < 32; e++) s = fmaf(wrow[e], vkb[e * 32], s);
            Mp[((size_t)b * 256 + co) * 512 + hd] = s;
        }
    }
}

// =====================================================================
// rden[bh][n] = 1 / (sum_d vk[bh][32][d] * relu(q[d][n]) + 1e-15)
// =====================================================================
__global__ __launch_bounds__(256)
void rden_k(const float* __restrict__ QKVb, const float* __restrict__ AGG2,
            const float* __restrict__ vk, float* __restrict__ Rden)
{
    const int n0 = blockIdx.x * 256;
    const int bh = blockIdx.y;
    const int b = bh >> 4, head = bh & 15;
    const float* base = (head < 8)
        ? QKVb + ((size_t)b * QKV + head * 96) * Nsp
        : AGG2 + ((size_t)b * QKV + (head - 8) * 96) * Nsp;
    const float* vk1 = vk + (size_t)bh * 1056 + 1024;
    const int t = threadIdx.x;
    float acc = 0;
#pragma unroll
    for (int d = 0; d < 32; d++)
        acc = fmaf(vk1[d], fmaxf(base[(size_t)d * Nsp + n0 + t], 0.f), acc);
    Rden[(size_t)bh * Nsp + n0 + t] = 1.0f / (acc + 1e-15f);
}

// =====================================================================
// Fused attention-out + proj + BN:
//   out[b][co][n] = BN( sum_{hd} Mp[b][co][hd] * relu(q[h,d,n])*rden[bh][n] )
// K-chunk k0 covers hd = k0..k0+31 -> h = k0/32 constant per chunk.
// =====================================================================
__global__ __launch_bounds__(256)
void gemm_proj(const float* __restrict__ QKVb, const float* __restrict__ AGG2,
               const float* __restrict__ Mp, const float* __restrict__ Rden,
               float* __restrict__ Y,
               const float* __restrict__ gamma, const float* __restrict__ beta,
               const float* __restrict__ rmean, const float* __restrict__ rvar)
{
    const int n0  = blockIdx.x * 128;
    const int co0 = blockIdx.y * 128;
    const int b   = blockIdx.z;
    const int t   = threadIdx.x;

    __shared__ float xs[32][128];
    __shared__ float wsh[32][128];

    float acc[8][8];
#pragma unroll
    for (int i = 0; i < 8; i++)
#pragma unroll
        for (int j = 0; j < 8; j++) acc[i][j] = 0.f;

    const int tn = t & 15;
    const int tc = t >> 4;
    const float* Wb = Mp + (size_t)b * 256 * 512;

    for (int k0 = 0; k0 < 512; k0 += 32) {
        const int h = k0 >> 5;                  // 0..15
        const float* qbase = (h < 8)
            ? QKVb + ((size_t)b * QKV + h * 96) * Nsp
            : AGG2 + ((size_t)b * QKV + (h - 8) * 96) * Nsp;
        const float* rd = Rden + (size_t)(b * 16 + h) * Nsp + n0;

        __syncthreads();
#pragma unroll
        for (int r = 0; r < 4; r++) {
            int id  = t + 256 * r;
            int row = id >> 5;                  // d = 0..31
            int q   = id & 31;
            float4 v = *reinterpret_cast<const float4*>(
                qbase + (size_t)row * Nsp + n0 + q * 4);
            float4 s = *reinterpret_cast<const float4*>(rd + q * 4);
            v.x = fmaxf(v.x, 0.f) * s.x;
            v.y = fmaxf(v.y, 0.f) * s.y;
            v.z = fmaxf(v.z, 0.f) * s.z;
            v.w = fmaxf(v.w, 0.f) * s.w;
            *reinterpret_cast<float4*>(&xs[row][q * 4]) = v;
        }
#pragma unroll
        for (int r = 0; r < 4; r++) {
            int id  = t + 256 * r;
            int coi = id >> 3;
            int cq  = id & 7;
            float4 v = *reinterpret_cast<const float4*>(
                Wb + (size_t)(co0 + coi) * 512 + k0 + cq * 4);
            wsh[cq * 4 + 0][coi] = v.x;
            wsh[cq * 4 + 1][coi] = v.y;
            wsh[cq * 4 + 2][coi] = v.z;
            wsh[cq * 4 + 3][coi] = v.w;
        }
        __syncthreads();
#pragma unroll 8
        for (int kk = 0; kk < 32; kk++) {
            float4 xa = *reinterpret_cast<const float4*>(&xs[kk][tn * 4]);
            float4 xb = *reinterpret_cast<const float4*>(&xs[kk][64 + tn * 4]);
            float4 wa = *reinterpret_cast<const float4*>(&wsh[kk][tc * 4]);
            float4 wb = *reinterpret_cast<const float4*>(&wsh[kk][64 + tc * 4]);
            float xr[8] = {xa.x, xa.y, xa.z, xa.w, xb.x, xb.y, xb.z, xb.w};
            float wr[8] = {wa.x, wa.y, wa.z, wa.w, wb.x, wb.y, wb.z, wb.w};
#pragma unroll
            for (int i = 0; i < 8; i++)
#pragma unroll
                for (int j = 0; j < 8; j++)
                    acc[i][j] = fmaf(wr[i], xr[j], acc[i][j]);
        }
    }

#pragma unroll
    for (int g = 0; g < 2; g++) {
#pragma unroll
        for (int j = 0; j < 4; j++) {
            int i  = g * 4 + j;
            int co = co0 + g * 64 + tc * 4 + j;
            float rs = rsqrtf(rvar[co] + 1e-5f);
            float sc = gamma[co] * rs;
            float sh = beta[co] - rmean[co] * sc;
            float* yp = Y + ((size_t)b * 256 + co) * Nsp + n0;
            float4 o0 = make_float4(fmaf(acc[i][0], sc, sh), fmaf(acc[i][1], sc, sh),
                                    fmaf(acc[i][2], sc, sh), fmaf(acc[i][3], sc, sh));
            float4 o1 = make_float4(fmaf(acc[i][4], sc, sh), fmaf(acc[i][5], sc, sh),
                                    fmaf(acc[i][6], sc, sh), fmaf(acc[i][7], sc, sh));
            *reinterpret_cast<float4*>(yp + tn * 4)      = o0;
            *reinterpret_cast<float4*>(yp + 64 + tn * 4) = o1;
        }
    }
}

// =====================================================================
extern "C" void kernel_launch(void* const* d_in, const int* in_sizes, int n_in,
                              void* d_out, int out_size, void* d_ws, size_t ws_size,
                              hipStream_t stream)
{
    const float* x      = (const float*)d_in[0];
    const float* w_qkv  = (const float*)d_in[1];
    const float* w_dw   = (const float*)d_in[2];
    const float* w_pw   = (const float*)d_in[3];
    const float* w_proj = (const float*)d_in[4];
    const float* gamma  = (const float*)d_in[5];
    const float* beta   = (const float*)d_in[6];
    const float* rmean  = (const float*)d_in[7];
    const float* rvar   = (const float*)d_in[8];
    float* out = (float*)d_out;

    const size_t SZf = (size_t)2 * QKV * Nsp;    // floats in full 2-batch buffer
    const size_t HBf = (size_t)QKV * Nsp;        // floats in 1-batch buffer
    float* qkv  = (float*)d_ws;                  // [0, SZf)
    float* agg2 = qkv + SZf;                     // [SZf, 2*SZf)
    float* aggH = agg2 + SZf;                    // [2*SZf, 2*SZf + HBf)  per-batch dw out
    // overlay region (aggH dead after pwconv(b=1)):
    float* vkp  = aggH;                          // 32*16*1056
    float* vkf  = vkp + (size_t)32 * 16 * 1056;  // 32*1056
    float* rden = vkf + (size_t)32 * 1056;       // 32*16384
    float* Mp   = rden + (size_t)32 * 16384;     // 2*256*512
    // peak = 2*SZf + HBf floats = 240 MiB

    dim3 blk(256);
    // 1) qkv = conv1x1(x)
    gemm1x1<<<dim3(128, 6, 2), blk, 0, stream>>>(x, w_qkv, qkv, 256, 768);
    // 2+3) per-batch: depthwise 5^3 -> half buffer, grouped pointwise -> agg2
    for (int b = 0; b < 2; b++) {
        dwconv5<<<dim3(768), blk, 0, stream>>>(qkv + (size_t)b * HBf, w_dw, aggH);
        pwconv<<<dim3(64, 24), blk, 0, stream>>>(aggH, w_pw, agg2 + (size_t)b * HBf);
    }
    // 4) vk partials + reduce (safe to overlay aggH: stream-ordered after pwconv)
    att_vk<<<dim3(16, 32), blk, 0, stream>>>(qkv, agg2, vkp);
    att_vk_reduce<<<dim3(32), blk, 0, stream>>>(vkp, vkf);
    // 5) M' = w_proj (x) vk  and  rden
    mprep<<<dim3(16, 2), blk, 0, stream>>>(w_proj, vkf, Mp);
    rden_k<<<dim3(64, 32), blk, 0, stream>>>(qkv, agg2, vkf, rden);
    // 6) fused attention-out + proj + BN
    gemm_proj<<<dim3(128, 2, 2), blk, 0, stream>>>(
        qkv, agg2, Mp, rden, out, gamma, beta, rmean, rvar);
}

// Round 5
// 403.128 us; speedup vs baseline: 2.0020x; 1.4589x over previous
//
#include <hip/hip_runtime.h>
#include <hip/hip_bf16.h>

// ---------------- problem constants ----------------
constexpr int QKV  = 768;     // 3*8*32
constexpr int Nsp  = 16384;   // 16*32*32

typedef __attribute__((ext_vector_type(8))) short short8_t;   // 8 bf16 (4 VGPR)
typedef __attribute__((ext_vector_type(4))) float f32x4;

__device__ inline unsigned short f2b(float f) {
    union { __hip_bfloat16 h; unsigned short u; } c;
    c.h = __float2bfloat16(f);
    return c.u;
}
__device__ inline float b2f(unsigned short u) {
    union { unsigned short u; __hip_bfloat16 h; } c;
    c.u = u;
    return __bfloat162float(c.h);
}
__device__ inline ushort4 f2b4(float4 v) {
    return make_ushort4(f2b(v.x), f2b(v.y), f2b(v.z), f2b(v.w));
}

// =====================================================================
// Elementwise f32 -> bf16 (for w_qkv). n4 = elements/4.
// =====================================================================
__global__ __launch_bounds__(256)
void cvt_bf16(const float* __restrict__ in, unsigned short* __restrict__ out, int n4)
{
    int i = blockIdx.x * 256 + threadIdx.x;
    if (i < n4) {
        float4 v = reinterpret_cast<const float4*>(in)[i];
        reinterpret_cast<ushort4*>(out)[i] = f2b4(v);
    }
}

// =====================================================================
// Tiled transpose f32 [C][N] -> bf16 [N][C], optional fused relu*rden.
// Input row for output col c: ((c>>5)-hBase)*GRP + (c&31).
//   x  : GRP=32, hBase=0  -> row c
//   q~ : GRP=96, hBase=0/8, rden != null, relu
// 64n x 64c tiles, LDS [64][66] f32 (2-way banks both phases).
// =====================================================================
__global__ __launch_bounds__(256)
void transposeT(const float* __restrict__ in, size_t inBStride,
                unsigned short* __restrict__ out, int Cout, int cBase,
                int GRP, int hBase, const float* __restrict__ rden)
{
    const int n0 = blockIdx.x * 64;
    const int c0 = cBase + blockIdx.y * 64;
    const int b  = blockIdx.z;
    const float* inb = in + (size_t)b * inBStride;

    __shared__ float tl[64][66];
    const int t = threadIdx.x;

#pragma unroll
    for (int r = 0; r < 8; r++) {
        int id = t + 256 * r;      // 0..2047
        int c  = id >> 5;          // 0..63
        int nh = id & 31;          // n-pair
        int cg = c0 + c;
        int inRow = ((cg >> 5) - hBase) * GRP + (cg & 31);
        float2 v = *reinterpret_cast<const float2*>(
            inb + (size_t)inRow * Nsp + n0 + nh * 2);
        if (rden) {
            float2 rv = *reinterpret_cast<const float2*>(
                rden + ((size_t)(b * 16 + (cg >> 5))) * Nsp + n0 + nh * 2);
            v.x = fmaxf(v.x, 0.f) * rv.x;
            v.y = fmaxf(v.y, 0.f) * rv.y;
        }
        tl[nh * 2 + 0][c] = v.x;
        tl[nh * 2 + 1][c] = v.y;
    }
    __syncthreads();

#pragma unroll
    for (int r = 0; r < 2; r++) {
        int id = t + 256 * r;      // 0..511
        int n  = id >> 3;          // 0..63
        int cq = id & 7;           // 8-elem group
        ushort4 lo = make_ushort4(f2b(tl[n][cq*8+0]), f2b(tl[n][cq*8+1]),
                                  f2b(tl[n][cq*8+2]), f2b(tl[n][cq*8+3]));
        ushort4 hi = make_ushort4(f2b(tl[n][cq*8+4]), f2b(tl[n][cq*8+5]),
                                  f2b(tl[n][cq*8+6]), f2b(tl[n][cq*8+7]));
        unsigned short* p = out + ((size_t)b * Nsp + n0 + n) * Cout + c0 + cq * 8;
        *reinterpret_cast<ushort4*>(p)     = lo;
        *reinterpret_cast<ushort4*>(p + 4) = hi;
    }
}

// =====================================================================
// bf16 MFMA GEMM: Y[b][co][n] f32 = A[co][k] x B^T[n][k], K-chunks of 32.
// 128x128 tile, 4 waves (2co x 2n), each 4x4 frags of 16x16x32.
// LDS [128][40] ushort (80 B rows -> <=2-way banks, 16 B aligned).
// =====================================================================
template<bool FUSE_BN>
__global__ __launch_bounds__(256)
void mfma_gemm(const unsigned short* __restrict__ A,
               const unsigned short* __restrict__ B,
               float* __restrict__ Y, int K, int M, size_t aBStride,
               const float* __restrict__ gamma, const float* __restrict__ beta,
               const float* __restrict__ rmean, const float* __restrict__ rvar)
{
    const int n0  = blockIdx.x * 128;
    const int co0 = blockIdx.y * 128;
    const int bz  = blockIdx.z;
    const int t   = threadIdx.x;

    __shared__ unsigned short a_lds[128][40];
    __shared__ unsigned short b_lds[128][40];

    const unsigned short* Ab = A + (size_t)bz * aBStride + (size_t)co0 * K;
    const unsigned short* Bb = B + ((size_t)bz * Nsp + n0) * K;

    const int lane = t & 63;
    const int wv   = t >> 6;
    const int wco  = wv >> 1;        // 0..1
    const int wn   = wv & 1;         // 0..1
    const int lr   = lane & 15;      // fragment row/col
    const int lg   = lane >> 4;      // k-group 0..3

    f32x4 acc[4][4];
#pragma unroll
    for (int m = 0; m < 4; m++)
#pragma unroll
        for (int f = 0; f < 4; f++) acc[m][f] = (f32x4){0.f, 0.f, 0.f, 0.f};

    for (int k0 = 0; k0 < K; k0 += 32) {
        __syncthreads();
#pragma unroll
        for (int r = 0; r < 2; r++) {
            int id  = t + 256 * r;   // 0..511
            int row = id >> 2;       // 0..127
            int kq  = id & 3;        // 8-ushort quad
            *reinterpret_cast<int4*>(&a_lds[row][kq * 8]) =
                *reinterpret_cast<const int4*>(Ab + (size_t)row * K + k0 + kq * 8);
            *reinterpret_cast<int4*>(&b_lds[row][kq * 8]) =
                *reinterpret_cast<const int4*>(Bb + (size_t)row * K + k0 + kq * 8);
        }
        __syncthreads();

        short8_t af[4], bf[4];
#pragma unroll
        for (int m = 0; m < 4; m++)
            af[m] = *reinterpret_cast<const short8_t*>(&a_lds[wco * 64 + m * 16 + lr][lg * 8]);
#pragma unroll
        for (int f = 0; f < 4; f++)
            bf[f] = *reinterpret_cast<const short8_t*>(&b_lds[wn * 64 + f * 16 + lr][lg * 8]);
#pragma unroll
        for (int m = 0; m < 4; m++)
#pragma unroll
            for (int f = 0; f < 4; f++)
                acc[m][f] = __builtin_amdgcn_mfma_f32_16x16x32_bf16(
                    af[m], bf[f], acc[m][f], 0, 0, 0);
    }

    // epilogue: C row = co0+wco*64+m*16+4*lg+j, col = n0+wn*64+f*16+lr
#pragma unroll
    for (int m = 0; m < 4; m++) {
#pragma unroll
        for (int j = 0; j < 4; j++) {
            int co = co0 + wco * 64 + m * 16 + 4 * lg + j;
            float sc = 1.f, sh = 0.f;
            if (FUSE_BN) {
                float rs = rsqrtf(rvar[co] + 1e-5f);
                sc = gamma[co] * rs;
                sh = beta[co] - rmean[co] * sc;
            }
            float* yp = Y + ((size_t)bz * M + co) * Nsp + n0 + wn * 64 + lr;
#pragma unroll
            for (int f = 0; f < 4; f++) {
                float v = acc[m][f][j];
                yp[f * 16] = FUSE_BN ? fmaf(v, sc, sh) : v;
            }
        }
    }
}

// =====================================================================
// Depthwise 5x5x5 conv, pad 2, SINGLE batch — plane-streaming.
// f32 in (qkv), bf16 out (aggH).
// =====================================================================
#define FMA4(A, WV, R, K)                \
    A.x = fmaf(WV, R[K + 0], A.x);       \
    A.y = fmaf(WV, R[K + 1], A.y);       \
    A.z = fmaf(WV, R[K + 2], A.z);       \
    A.w = fmaf(WV, R[K + 3], A.w);

#define PLANE_STEP(Z, G0, G1, G2, G3, G4, DOWRITE, DOSTAGE)                   \
  {                                                                           \
    const int zz  = (Z);                                                      \
    const int cur = zz & 1;                                                   \
    __syncthreads();                                                          \
    float4 g = {0.f, 0.f, 0.f, 0.f};                                          \
    if (DOSTAGE)                                                              \
      g = *reinterpret_cast<const float4*>(Xc + (zz + 1) * 1024 +             \
                                           hrow * 32 + w4);                   \
    _Pragma("unroll")                                                         \
    for (int kh = 0; kh < 5; kh++) {                                          \
      const float* rp = &pl[cur][hrow + kh][w4];                              \
      float4 c0 = *reinterpret_cast<const float4*>(rp);                       \
      float4 c1 = *reinterpret_cast<const float4*>(rp + 4);                   \
      float r[8] = {c0.x, c0.y, c0.z, c0.w, c1.x, c1.y, c1.z, c1.w};          \
      _Pragma("unroll")                                                       \
      for (int kw = 0; kw < 5; kw++) {                                        \
        if (G0) { float wv = wr[  0 + kh * 5 + kw]; FMA4(a0, wv, r, kw) }     \
        if (G1) { float wv = wr[ 25 + kh * 5 + kw]; FMA4(a1, wv, r, kw) }     \
        if (G2) { float wv = wr[ 50 + kh * 5 + kw]; FMA4(a2, wv, r, kw) }     \
        if (G3) { float wv = wr[ 75 + kh * 5 + kw]; FMA4(a3, wv, r, kw) }     \
        if (G4) { float wv = wr[100 + kh * 5 + kw]; FMA4(a4, wv, r, kw) }     \
      }                                                                       \
    }                                                                         \
    if (DOWRITE)                                                              \
      *reinterpret_cast<ushort4*>(Yc + ((zz - 2) * 32 + hrow) * 32 + w4)      \
          = f2b4(a4);                                                         \
    a4 = a3; a3 = a2; a2 = a1; a1 = a0;                                       \
    a0.x = 0.f; a0.y = 0.f; a0.z = 0.f; a0.w = 0.f;                           \
    if (DOSTAGE) {                                                            \
      const int nxt = cur ^ 1;                                                \
      pl[nxt][hrow + 2][2 + w4 + 0] = g.x;                                    \
      pl[nxt][hrow + 2][2 + w4 + 1] = g.y;                                    \
      pl[nxt][hrow + 2][2 + w4 + 2] = g.z;                                    \
      pl[nxt][hrow + 2][2 + w4 + 3] = g.w;                                    \
    }                                                                         \
  }

__global__ __launch_bounds__(256)
void dwconv5(const float* __restrict__ X, const float* __restrict__ Wd,
             unsigned short* __restrict__ Y)
{
    const int ch = blockIdx.x;      // 0..767
    const int t  = threadIdx.x;

    __shared__ float pl[2][36][40];

    const float* Xc = X + (size_t)ch * Nsp;
    unsigned short* Yc = Y + (size_t)ch * Nsp;
    const float* wp = Wd + ch * 125;

    float wr[125];
#pragma unroll
    for (int i = 0; i < 125; i++) wr[i] = wp[i];

    for (int i = t; i < 2 * 36 * 40; i += 256)
        (&pl[0][0][0])[i] = 0.f;

    const int hrow = t >> 3;
    const int w4   = (t & 7) * 4;

    __syncthreads();
    {
        float4 g = *reinterpret_cast<const float4*>(Xc + hrow * 32 + w4);
        pl[0][hrow + 2][2 + w4 + 0] = g.x;
        pl[0][hrow + 2][2 + w4 + 1] = g.y;
        pl[0][hrow + 2][2 + w4 + 2] = g.z;
        pl[0][hrow + 2][2 + w4 + 3] = g.w;
    }

    float4 a0 = {0,0,0,0}, a1 = a0, a2 = a0, a3 = a0, a4 = a0;

    PLANE_STEP(0, true, true, true, false, false, false, true)
    PLANE_STEP(1, true, true, true, true,  false, false, true)
#pragma unroll 1
    for (int z = 2; z <= 13; z++) {
        PLANE_STEP(z, true, true, true, true, true, true, true)
    }
    PLANE_STEP(14, false, true,  true, true, true, true, true)
    PLANE_STEP(15, false, false, true, true, true, true, false)
    *reinterpret_cast<ushort4*>(Yc + ((14 * 32 + hrow) * 32 + w4)) = f2b4(a4);
    *reinterpret_cast<ushort4*>(Yc + ((15 * 32 + hrow) * 32 + w4)) = f2b4(a3);
}

// =====================================================================
// Grouped pointwise conv (single batch): bf16 in, f32 out.
// =====================================================================
__global__ __launch_bounds__(256)
void pwconv(const unsigned short* __restrict__ X, const float* __restrict__ Wp,
            float* __restrict__ Y)
{
    const int n0 = blockIdx.x * 256;
    const int g  = blockIdx.y;      // 0..23
    const int t  = threadIdx.x;
    const int lane = t & 63, wv = t >> 6;

    __shared__ float xs[32][256];

    const unsigned short* Xg = X + (size_t)(g * 32) * Nsp + n0;
#pragma unroll
    for (int rr = 0; rr < 8; rr++) {
        int r = wv + rr * 4;
        ushort4 u = *reinterpret_cast<const ushort4*>(Xg + (size_t)r * Nsp + lane * 4);
        float4 v = make_float4(b2f(u.x), b2f(u.y), b2f(u.z), b2f(u.w));
        *reinterpret_cast<float4*>(&xs[r][lane * 4]) = v;
    }
    __syncthreads();

    float xin[32];
#pragma unroll
    for (int j = 0; j < 32; j++) xin[j] = xs[j][t];

    const float* wg = Wp + g * 1024;
    float* Yg = Y + (size_t)(g * 32) * Nsp + n0;
#pragma unroll 4
    for (int co = 0; co < 32; co++) {
        float acc = 0;
#pragma unroll
        for (int j = 0; j < 32; j++) acc = fmaf(wg[co * 32 + j], xin[j], acc);
        Yg[(size_t)co * Nsp + t] = acc;
    }
}

// =====================================================================
// Attention phase 1: vk[e][d] partials, 16 chunks x 1024 n each.
// =====================================================================
__global__ __launch_bounds__(256)
void att_vk(const float* __restrict__ QKVb, const float* __restrict__ AGG2,
            float* __restrict__ vk_part)
{
    const int chunk = blockIdx.x;   // 0..15
    const int bh    = blockIdx.y;   // 0..31
    const int b = bh >> 4, head = bh & 15;
    const float* base = (head < 8)
        ? QKVb + ((size_t)b * QKV + head * 96) * Nsp
        : AGG2 + ((size_t)b * QKV + (head - 8) * 96) * Nsp;

    __shared__ float ks[32][256];
    __shared__ float vs[32][256];

    const int t = threadIdx.x;
    const int lane = t & 63, wv = t >> 6;
    const int a  = t & 15;
    const int e0 = t >> 4;          // 0..15
    const int d0 = 2 * a;
    const int rot = (2 * d0 + 34 * e0) & 255;

    float a00 = 0, a01 = 0, a10 = 0, a11 = 0, s0 = 0, s1 = 0;

    for (int sub = 0; sub < 4; sub++) {
        const int n0 = chunk * 1024 + sub * 256;
        __syncthreads();
#pragma unroll
        for (int rr = 0; rr < 16; rr++) {
            int rid = wv + rr * 4;      // 0..63
            if (rid < 32) {
                float4 v = *reinterpret_cast<const float4*>(
                    base + (size_t)(32 + rid) * Nsp + n0 + lane * 4);
                v.x = fmaxf(v.x, 0.f); v.y = fmaxf(v.y, 0.f);
                v.z = fmaxf(v.z, 0.f); v.w = fmaxf(v.w, 0.f);
                *reinterpret_cast<float4*>(&ks[rid][lane * 4]) = v;
            } else {
                float4 v = *reinterpret_cast<const float4*>(
                    base + (size_t)(64 + rid - 32) * Nsp + n0 + lane * 4);
                *reinterpret_cast<float4*>(&vs[rid - 32][lane * 4]) = v;
            }
        }
        __syncthreads();

#pragma unroll 4
        for (int n = 0; n < 256; n += 2) {
            int nn = (n + rot) & 255;
            float2 k0 = *reinterpret_cast<const float2*>(&ks[d0][nn]);
            float2 k1 = *reinterpret_cast<const float2*>(&ks[d0 + 1][nn]);
            float2 v0 = *reinterpret_cast<const float2*>(&vs[e0][nn]);
            float2 v1 = *reinterpret_cast<const float2*>(&vs[e0 + 16][nn]);
            a00 = fmaf(v0.x, k0.x, fmaf(v0.y, k0.y, a00));
            a01 = fmaf(v0.x, k1.x, fmaf(v0.y, k1.y, a01));
            a10 = fmaf(v1.x, k0.x, fmaf(v1.y, k0.y, a10));
            a11 = fmaf(v1.x, k1.x, fmaf(v1.y, k1.y, a11));
            s0 += k0.x + k0.y;
            s1 += k1.x + k1.y;
        }
    }

    float* vp = vk_part + ((size_t)bh * 16 + chunk) * 1056;
    vp[e0 * 32 + d0]            = a00;
    vp[e0 * 32 + d0 + 1]        = a01;
    vp[(e0 + 16) * 32 + d0]     = a10;
    vp[(e0 + 16) * 32 + d0 + 1] = a11;
    if (e0 == 0) {
        vp[32 * 32 + d0]     = s0;
        vp[32 * 32 + d0 + 1] = s1;
    }
}

// Reduce the 16 chunk partials -> vk[bh][33][32]
__global__ __launch_bounds__(256)
void att_vk_reduce(const float* __restrict__ vk_part, float* __restrict__ vk)
{
    const int bh = blockIdx.x;
    const int t  = threadIdx.x;
    for (int id = t; id < 1056; id += 256) {
        const float* p = vk_part + (size_t)bh * 16 * 1056 + id;
        float s = 0;
#pragma unroll
        for (int c = 0; c < 16; c++) s += p[(size_t)c * 1056];
        vk[bh * 1056 + id] = s;
    }
}

// =====================================================================
// M'[b][co][h*32+d] = sum_e w_proj[co][h*32+e] * vk[b*16+h][e][d]  (bf16 out)
// =====================================================================
__global__ __launch_bounds__(256)
void mprep(const float* __restrict__ Wproj, const float* __restrict__ vk,
           unsigned short* __restrict__ Mp)
{
    const int b   = blockIdx.y;
    const int co0 = blockIdx.x * 16;
    const int t   = threadIdx.x;
    for (int ci = 0; ci < 16; ci++) {
        int co = co0 + ci;
        for (int hd = t; hd < 512; hd += 256) {
            int h = hd >> 5, d = hd & 31;
            const float* wrow = Wproj + (size_t)co * 512 + h * 32;
            const float* vkb  = vk + (size_t)(b * 16 + h) * 1056 + d;
            float s = 0;
#pragma unroll
            for (int e = 0; e < 32; e++) s = fmaf(wrow[e], vkb[e * 32], s);
            Mp[((size_t)b * 256 + co) * 512 + hd] = f2b(s);
        }
    }
}

// =====================================================================
// rden[bh][n] = 1 / (sum_d vk[bh][32][d] * relu(q[d][n]) + 1e-15)
// =====================================================================
__global__ __launch_bounds__(256)
void rden_k(const float* __restrict__ QKVb, const float* __restrict__ AGG2,
            const float* __restrict__ vk, float* __restrict__ Rden)
{
    const int n0 = blockIdx.x * 256;
    const int bh = blockIdx.y;
    const int b = bh >> 4, head = bh & 15;
    const float* base = (head < 8)
        ? QKVb + ((size_t)b * QKV + head * 96) * Nsp
        : AGG2 + ((size_t)b * QKV + (head - 8) * 96) * Nsp;
    const float* vk1 = vk + (size_t)bh * 1056 + 1024;
    const int t = threadIdx.x;
    float acc = 0;
#pragma unroll
    for (int d = 0; d < 32; d++)
        acc = fmaf(vk1[d], fmaxf(base[(size_t)d * Nsp + n0 + t], 0.f), acc);
    Rden[(size_t)bh * Nsp + n0 + t] = 1.0f / (acc + 1e-15f);
}

// =====================================================================
extern "C" void kernel_launch(void* const* d_in, const int* in_sizes, int n_in,
                              void* d_out, int out_size, void* d_ws, size_t ws_size,
                              hipStream_t stream)
{
    const float* x      = (const float*)d_in[0];
    const float* w_qkv  = (const float*)d_in[1];
    const float* w_dw   = (const float*)d_in[2];
    const float* w_pw   = (const float*)d_in[3];
    const float* w_proj = (const float*)d_in[4];
    const float* gamma  = (const float*)d_in[5];
    const float* beta   = (const float*)d_in[6];
    const float* rmean  = (const float*)d_in[7];
    const float* rvar   = (const float*)d_in[8];
    float* out = (float*)d_out;

    const size_t SZ = (size_t)2 * QKV * Nsp * sizeof(float);     // 100.66 MB
    const size_t RB = (size_t)2 * Nsp * 512 * sizeof(unsigned short); // 33.55 MB
    char* ws = (char*)d_ws;
    float* qkv  = (float*)ws;                    // f32 [2][768][16384]
    float* agg2 = (float*)(ws + SZ);             // f32 [2][768][16384]
    char*  Rb   = ws + 2 * SZ;                   // time-shared region (33.55 MB)
    unsigned short* xT   = (unsigned short*)Rb;  // [2][16384][256] bf16 (steps 2-3)
    unsigned short* aggH = (unsigned short*)Rb;  // [768][16384]  bf16 (step 4)
    unsigned short* qT   = (unsigned short*)Rb;  // [2][16384][512] bf16 (steps 8-9)
    char* slab = Rb + RB;
    float* vkp  = (float*)slab;                          // 32*16*1056
    float* vkf  = vkp + (size_t)32 * 16 * 1056;          // 32*1056
    float* rden = vkf + (size_t)32 * 1056;               // 32*16384
    unsigned short* Mp  = (unsigned short*)(rden + (size_t)32 * 16384); // 2*256*512
    unsigned short* wqb = Mp + (size_t)2 * 256 * 512;    // 768*256
    // total ws use ~240.2 MB (== previous passing peak)

    dim3 blk(256);
    // 1) weights -> bf16
    cvt_bf16<<<dim3(192), blk, 0, stream>>>(w_qkv, wqb, 768 * 256 / 4);
    // 2) xT = transpose(x) bf16
    transposeT<<<dim3(256, 4, 2), blk, 0, stream>>>(
        x, (size_t)256 * Nsp, xT, 256, 0, 32, 0, nullptr);
    // 3) qkv = wqb x xT   (MFMA)
    mfma_gemm<false><<<dim3(128, 6, 2), blk, 0, stream>>>(
        wqb, xT, qkv, 256, 768, 0, nullptr, nullptr, nullptr, nullptr);
    // 4) per-batch: depthwise (bf16 out) -> grouped pointwise (f32 out)
    for (int b = 0; b < 2; b++) {
        dwconv5<<<dim3(768), blk, 0, stream>>>(
            qkv + (size_t)b * QKV * Nsp, w_dw, aggH);
        pwconv<<<dim3(64, 24), blk, 0, stream>>>(
            aggH, w_pw, agg2 + (size_t)b * QKV * Nsp);
    }
    // 5) vk partials + reduce
    att_vk<<<dim3(16, 32), blk, 0, stream>>>(qkv, agg2, vkp);
    att_vk_reduce<<<dim3(32), blk, 0, stream>>>(vkp, vkf);
    // 6) M' (bf16) and rden
    mprep<<<dim3(16, 2), blk, 0, stream>>>(w_proj, vkf, Mp);
    rden_k<<<dim3(64, 32), blk, 0, stream>>>(qkv, agg2, vkf, rden);
    // 7) q~T = transpose(relu(q)*rden) bf16, both halves
    transposeT<<<dim3(256, 4, 2), blk, 0, stream>>>(
        qkv, (size_t)QKV * Nsp, qT, 512, 0, 96, 0, rden);
    transposeT<<<dim3(256, 4, 2), blk, 0, stream>>>(
        agg2, (size_t)QKV * Nsp, qT, 512, 256, 96, 8, rden);
    // 8) out = Mp x q~T + BN   (MFMA)
    mfma_gemm<true><<<dim3(128, 2, 2), blk, 0, stream>>>(
        Mp, qT, out, 512, 256, (size_t)256 * 512,
        gamma, beta, rmean, rvar);
}

// Round 6
// 362.997 us; speedup vs baseline: 2.2234x; 1.1106x over previous
//
#include <hip/hip_runtime.h>
#include <hip/hip_bf16.h>

// ---------------- problem constants ----------------
constexpr int QKV  = 768;     // 3*8*32
constexpr int Nsp  = 16384;   // 16*32*32

typedef __attribute__((ext_vector_type(8))) short short8_t;            // 8 bf16
typedef __attribute__((ext_vector_type(8))) unsigned short ushort8_t;  // 8 bf16
typedef __attribute__((ext_vector_type(4))) float f32x4;

__device__ inline unsigned short f2b(float f) {
    union { __hip_bfloat16 h; unsigned short u; } c;
    c.h = __float2bfloat16(f);
    return c.u;
}
__device__ inline float b2f(unsigned short u) {   // exact: bf16 -> f32 is a shift
    unsigned v = (unsigned)u << 16;
    float f;
    __builtin_memcpy(&f, &v, 4);
    return f;
}
__device__ inline ushort4 f2b4(float4 v) {
    return make_ushort4(f2b(v.x), f2b(v.y), f2b(v.z), f2b(v.w));
}

// =====================================================================
// Elementwise f32 -> bf16 (for w_qkv). n4 = elements/4.
// =====================================================================
__global__ __launch_bounds__(256)
void cvt_bf16(const float* __restrict__ in, unsigned short* __restrict__ out, int n4)
{
    int i = blockIdx.x * 256 + threadIdx.x;
    if (i < n4) {
        float4 v = reinterpret_cast<const float4*>(in)[i];
        reinterpret_cast<ushort4*>(out)[i] = f2b4(v);
    }
}

// =====================================================================
// Tiled transpose [C][N] -> bf16 [N][C], optional fused relu*rden.
// Input row for output col c: ((c>>5)-hBase)*GRP + (c&31).
// IN_BF16 selects input element type.
// =====================================================================
template<bool IN_BF16>
__global__ __launch_bounds__(256)
void transposeT(const void* __restrict__ in_, size_t inBStride,
                unsigned short* __restrict__ out, int Cout, int cBase,
                int GRP, int hBase, const float* __restrict__ rden)
{
    const int n0 = blockIdx.x * 64;
    const int c0 = cBase + blockIdx.y * 64;
    const int b  = blockIdx.z;

    __shared__ float tl[64][66];
    const int t = threadIdx.x;

#pragma unroll
    for (int r = 0; r < 8; r++) {
        int id = t + 256 * r;      // 0..2047
        int c  = id >> 5;          // 0..63
        int nh = id & 31;          // n-pair
        int cg = c0 + c;
        int inRow = ((cg >> 5) - hBase) * GRP + (cg & 31);
        float2 v;
        if (IN_BF16) {
            const unsigned short* inb = (const unsigned short*)in_ + (size_t)b * inBStride;
            ushort2 u = *reinterpret_cast<const ushort2*>(
                inb + (size_t)inRow * Nsp + n0 + nh * 2);
            v.x = b2f(u.x); v.y = b2f(u.y);
        } else {
            const float* inb = (const float*)in_ + (size_t)b * inBStride;
            v = *reinterpret_cast<const float2*>(
                inb + (size_t)inRow * Nsp + n0 + nh * 2);
        }
        if (rden) {
            float2 rv = *reinterpret_cast<const float2*>(
                rden + ((size_t)(b * 16 + (cg >> 5))) * Nsp + n0 + nh * 2);
            v.x = fmaxf(v.x, 0.f) * rv.x;
            v.y = fmaxf(v.y, 0.f) * rv.y;
        }
        tl[nh * 2 + 0][c] = v.x;
        tl[nh * 2 + 1][c] = v.y;
    }
    __syncthreads();

#pragma unroll
    for (int r = 0; r < 2; r++) {
        int id = t + 256 * r;      // 0..511
        int n  = id >> 3;          // 0..63
        int cq = id & 7;           // 8-elem group
        ushort4 lo = make_ushort4(f2b(tl[n][cq*8+0]), f2b(tl[n][cq*8+1]),
                                  f2b(tl[n][cq*8+2]), f2b(tl[n][cq*8+3]));
        ushort4 hi = make_ushort4(f2b(tl[n][cq*8+4]), f2b(tl[n][cq*8+5]),
                                  f2b(tl[n][cq*8+6]), f2b(tl[n][cq*8+7]));
        unsigned short* p = out + ((size_t)b * Nsp + n0 + n) * Cout + c0 + cq * 8;
        *reinterpret_cast<ushort4*>(p)     = lo;
        *reinterpret_cast<ushort4*>(p + 4) = hi;
    }
}

// =====================================================================
// bf16 MFMA GEMM: Y[b][co][n] = A[co][k] x B^T[n][k], K-chunks of 32.
// 128x128 tile, 4 waves (2co x 2n), each 4x4 frags of 16x16x32.
// OUT_BF16 selects output type (bf16 for qkv, f32+BN for final).
// =====================================================================
template<bool FUSE_BN, bool OUT_BF16>
__global__ __launch_bounds__(256)
void mfma_gemm(const unsigned short* __restrict__ A,
               const unsigned short* __restrict__ B,
               void* __restrict__ Yv, int K, int M, size_t aBStride,
               const float* __restrict__ gamma, const float* __restrict__ beta,
               const float* __restrict__ rmean, const float* __restrict__ rvar)
{
    const int n0  = blockIdx.x * 128;
    const int co0 = blockIdx.y * 128;
    const int bz  = blockIdx.z;
    const int t   = threadIdx.x;

    __shared__ unsigned short a_lds[128][40];
    __shared__ unsigned short b_lds[128][40];

    const unsigned short* Ab = A + (size_t)bz * aBStride + (size_t)co0 * K;
    const unsigned short* Bb = B + ((size_t)bz * Nsp + n0) * K;

    const int lane = t & 63;
    const int wv   = t >> 6;
    const int wco  = wv >> 1;        // 0..1
    const int wn   = wv & 1;         // 0..1
    const int lr   = lane & 15;      // fragment row/col
    const int lg   = lane >> 4;      // k-group 0..3

    f32x4 acc[4][4];
#pragma unroll
    for (int m = 0; m < 4; m++)
#pragma unroll
        for (int f = 0; f < 4; f++) acc[m][f] = (f32x4){0.f, 0.f, 0.f, 0.f};

    for (int k0 = 0; k0 < K; k0 += 32) {
        __syncthreads();
#pragma unroll
        for (int r = 0; r < 2; r++) {
            int id  = t + 256 * r;   // 0..511
            int row = id >> 2;       // 0..127
            int kq  = id & 3;        // 8-ushort quad
            *reinterpret_cast<int4*>(&a_lds[row][kq * 8]) =
                *reinterpret_cast<const int4*>(Ab + (size_t)row * K + k0 + kq * 8);
            *reinterpret_cast<int4*>(&b_lds[row][kq * 8]) =
                *reinterpret_cast<const int4*>(Bb + (size_t)row * K + k0 + kq * 8);
        }
        __syncthreads();

        short8_t af[4], bf[4];
#pragma unroll
        for (int m = 0; m < 4; m++)
            af[m] = *reinterpret_cast<const short8_t*>(&a_lds[wco * 64 + m * 16 + lr][lg * 8]);
#pragma unroll
        for (int f = 0; f < 4; f++)
            bf[f] = *reinterpret_cast<const short8_t*>(&b_lds[wn * 64 + f * 16 + lr][lg * 8]);
#pragma unroll
        for (int m = 0; m < 4; m++)
#pragma unroll
            for (int f = 0; f < 4; f++)
                acc[m][f] = __builtin_amdgcn_mfma_f32_16x16x32_bf16(
                    af[m], bf[f], acc[m][f], 0, 0, 0);
    }

    // epilogue: C row = co0+wco*64+m*16+4*lg+j, col = n0+wn*64+f*16+lr
#pragma unroll
    for (int m = 0; m < 4; m++) {
#pragma unroll
        for (int j = 0; j < 4; j++) {
            int co = co0 + wco * 64 + m * 16 + 4 * lg + j;
            float sc = 1.f, sh = 0.f;
            if (FUSE_BN) {
                float rs = rsqrtf(rvar[co] + 1e-5f);
                sc = gamma[co] * rs;
                sh = beta[co] - rmean[co] * sc;
            }
            if (OUT_BF16) {
                unsigned short* yp = (unsigned short*)Yv +
                    ((size_t)bz * M + co) * Nsp + n0 + wn * 64 + lr;
#pragma unroll
                for (int f = 0; f < 4; f++) yp[f * 16] = f2b(acc[m][f][j]);
            } else {
                float* yp = (float*)Yv +
                    ((size_t)bz * M + co) * Nsp + n0 + wn * 64 + lr;
#pragma unroll
                for (int f = 0; f < 4; f++) {
                    float v = acc[m][f][j];
                    yp[f * 16] = FUSE_BN ? fmaf(v, sc, sh) : v;
                }
            }
        }
    }
}

// =====================================================================
// Depthwise 5x5x5 conv, pad 2 — plane-streaming, BOTH batches.
// bf16 in, bf16 out; compute f32 (weights land in SGPRs).
// =====================================================================
#define FMA4(A, WV, R, K)                \
    A.x = fmaf(WV, R[K + 0], A.x);       \
    A.y = fmaf(WV, R[K + 1], A.y);       \
    A.z = fmaf(WV, R[K + 2], A.z);       \
    A.w = fmaf(WV, R[K + 3], A.w);

#define PLANE_STEP(Z, G0, G1, G2, G3, G4, DOWRITE, DOSTAGE)                   \
  {                                                                           \
    const int zz  = (Z);                                                      \
    const int cur = zz & 1;                                                   \
    __syncthreads();                                                          \
    ushort4 gu = make_ushort4(0, 0, 0, 0);                                    \
    if (DOSTAGE)                                                              \
      gu = *reinterpret_cast<const ushort4*>(Xc + (zz + 1) * 1024 +           \
                                             hrow * 32 + w4);                 \
    _Pragma("unroll")                                                         \
    for (int kh = 0; kh < 5; kh++) {                                          \
      const float* rp = &pl[cur][hrow + kh][w4];                              \
      float4 c0 = *reinterpret_cast<const float4*>(rp);                       \
      float4 c1 = *reinterpret_cast<const float4*>(rp + 4);                   \
      float r[8] = {c0.x, c0.y, c0.z, c0.w, c1.x, c1.y, c1.z, c1.w};          \
      _Pragma("unroll")                                                       \
      for (int kw = 0; kw < 5; kw++) {                                        \
        if (G0) { float wv = wr[  0 + kh * 5 + kw]; FMA4(a0, wv, r, kw) }     \
        if (G1) { float wv = wr[ 25 + kh * 5 + kw]; FMA4(a1, wv, r, kw) }     \
        if (G2) { float wv = wr[ 50 + kh * 5 + kw]; FMA4(a2, wv, r, kw) }     \
        if (G3) { float wv = wr[ 75 + kh * 5 + kw]; FMA4(a3, wv, r, kw) }     \
        if (G4) { float wv = wr[100 + kh * 5 + kw]; FMA4(a4, wv, r, kw) }     \
      }                                                                       \
    }                                                                         \
    if (DOWRITE)                                                              \
      *reinterpret_cast<ushort4*>(Yc + ((zz - 2) * 32 + hrow) * 32 + w4)      \
          = f2b4(a4);                                                         \
    a4 = a3; a3 = a2; a2 = a1; a1 = a0;                                       \
    a0.x = 0.f; a0.y = 0.f; a0.z = 0.f; a0.w = 0.f;                           \
    if (DOSTAGE) {                                                            \
      const int nxt = cur ^ 1;                                                \
      pl[nxt][hrow + 2][2 + w4 + 0] = b2f(gu.x);                              \
      pl[nxt][hrow + 2][2 + w4 + 1] = b2f(gu.y);                              \
      pl[nxt][hrow + 2][2 + w4 + 2] = b2f(gu.z);                              \
      pl[nxt][hrow + 2][2 + w4 + 3] = b2f(gu.w);                              \
    }                                                                         \
  }

__global__ __launch_bounds__(256)
void dwconv5(const unsigned short* __restrict__ X, const float* __restrict__ Wd,
             unsigned short* __restrict__ Y)
{
    const int ch = blockIdx.x;      // 0..767
    const int b  = blockIdx.y;      // 0..1
    const int t  = threadIdx.x;

    __shared__ float pl[2][36][40];

    const unsigned short* Xc = X + ((size_t)b * QKV + ch) * Nsp;
    unsigned short*       Yc = Y + ((size_t)b * QKV + ch) * Nsp;
    const float* wp = Wd + ch * 125;

    float wr[125];
#pragma unroll
    for (int i = 0; i < 125; i++) wr[i] = wp[i];

    for (int i = t; i < 2 * 36 * 40; i += 256)
        (&pl[0][0][0])[i] = 0.f;

    const int hrow = t >> 3;
    const int w4   = (t & 7) * 4;

    __syncthreads();
    {
        ushort4 gu = *reinterpret_cast<const ushort4*>(Xc + hrow * 32 + w4);
        pl[0][hrow + 2][2 + w4 + 0] = b2f(gu.x);
        pl[0][hrow + 2][2 + w4 + 1] = b2f(gu.y);
        pl[0][hrow + 2][2 + w4 + 2] = b2f(gu.z);
        pl[0][hrow + 2][2 + w4 + 3] = b2f(gu.w);
    }

    float4 a0 = {0,0,0,0}, a1 = a0, a2 = a0, a3 = a0, a4 = a0;

    PLANE_STEP(0, true, true, true, false, false, false, true)
    PLANE_STEP(1, true, true, true, true,  false, false, true)
#pragma unroll 1
    for (int z = 2; z <= 13; z++) {
        PLANE_STEP(z, true, true, true, true, true, true, true)
    }
    PLANE_STEP(14, false, true,  true, true, true, true, true)
    PLANE_STEP(15, false, false, true, true, true, true, false)
    *reinterpret_cast<ushort4*>(Yc + ((14 * 32 + hrow) * 32 + w4)) = f2b4(a4);
    *reinterpret_cast<ushort4*>(Yc + ((15 * 32 + hrow) * 32 + w4)) = f2b4(a3);
}

// =====================================================================
// Grouped pointwise conv, both batches: bf16 in, bf16 out.
// =====================================================================
__global__ __launch_bounds__(256)
void pwconv(const unsigned short* __restrict__ X, const float* __restrict__ Wp,
            unsigned short* __restrict__ Y)
{
    const int n0 = blockIdx.x * 256;
    const int g  = blockIdx.y;      // 0..23
    const int bz = blockIdx.z;
    const int t  = threadIdx.x;
    const int lane = t & 63, wv = t >> 6;

    __shared__ float xs[32][256];

    const unsigned short* Xg = X + ((size_t)bz * QKV + g * 32) * Nsp + n0;
#pragma unroll
    for (int rr = 0; rr < 8; rr++) {
        int r = wv + rr * 4;
        ushort4 u = *reinterpret_cast<const ushort4*>(Xg + (size_t)r * Nsp + lane * 4);
        xs[r][lane * 4 + 0] = b2f(u.x);
        xs[r][lane * 4 + 1] = b2f(u.y);
        xs[r][lane * 4 + 2] = b2f(u.z);
        xs[r][lane * 4 + 3] = b2f(u.w);
    }
    __syncthreads();

    float xin[32];
#pragma unroll
    for (int j = 0; j < 32; j++) xin[j] = xs[j][t];

    const float* wg = Wp + g * 1024;
    unsigned short* Yg = Y + ((size_t)bz * QKV + g * 32) * Nsp + n0;
#pragma unroll 4
    for (int co = 0; co < 32; co++) {
        float acc = 0;
#pragma unroll
        for (int j = 0; j < 32; j++) acc = fmaf(wg[co * 32 + j], xin[j], acc);
        Yg[(size_t)co * Nsp + t] = f2b(acc);
    }
}

// =====================================================================
// Attention phase 1: vk[e][d] partials, 16 chunks x 1024 n each.
// bf16 inputs -> f32 LDS -> f32 accumulate.
// =====================================================================
__global__ __launch_bounds__(256)
void att_vk(const unsigned short* __restrict__ QKVb,
            const unsigned short* __restrict__ AGG2,
            float* __restrict__ vk_part)
{
    const int chunk = blockIdx.x;   // 0..15
    const int bh    = blockIdx.y;   // 0..31
    const int b = bh >> 4, head = bh & 15;
    const unsigned short* base = (head < 8)
        ? QKVb + ((size_t)b * QKV + head * 96) * Nsp
        : AGG2 + ((size_t)b * QKV + (head - 8) * 96) * Nsp;

    __shared__ float ks[32][256];
    __shared__ float vs[32][256];

    const int t = threadIdx.x;
    const int a  = t & 15;
    const int e0 = t >> 4;          // 0..15
    const int d0 = 2 * a;
    const int rot = (2 * d0 + 34 * e0) & 255;

    float a00 = 0, a01 = 0, a10 = 0, a11 = 0, s0 = 0, s1 = 0;

    for (int sub = 0; sub < 4; sub++) {
        const int n0 = chunk * 1024 + sub * 256;
        __syncthreads();
#pragma unroll
        for (int rr = 0; rr < 8; rr++) {
            int id  = t + 256 * rr;     // 0..2047
            int rid = id >> 5;          // 0..63: k rows 0-31, v rows 32-63
            int cg  = id & 31;          // 8-col group
            ushort8_t u = *reinterpret_cast<const ushort8_t*>(
                base + (size_t)(32 + rid) * Nsp + n0 + cg * 8);
            float f[8];
#pragma unroll
            for (int j = 0; j < 8; j++) f[j] = b2f(u[j]);
            if (rid < 32) {
#pragma unroll
                for (int j = 0; j < 8; j++) ks[rid][cg * 8 + j] = fmaxf(f[j], 0.f);
            } else {
#pragma unroll
                for (int j = 0; j < 8; j++) vs[rid - 32][cg * 8 + j] = f[j];
            }
        }
        __syncthreads();

#pragma unroll 4
        for (int n = 0; n < 256; n += 2) {
            int nn = (n + rot) & 255;
            float2 k0 = *reinterpret_cast<const float2*>(&ks[d0][nn]);
            float2 k1 = *reinterpret_cast<const float2*>(&ks[d0 + 1][nn]);
            float2 v0 = *reinterpret_cast<const float2*>(&vs[e0][nn]);
            float2 v1 = *reinterpret_cast<const float2*>(&vs[e0 + 16][nn]);
            a00 = fmaf(v0.x, k0.x, fmaf(v0.y, k0.y, a00));
            a01 = fmaf(v0.x, k1.x, fmaf(v0.y, k1.y, a01));
            a10 = fmaf(v1.x, k0.x, fmaf(v1.y, k0.y, a10));
            a11 = fmaf(v1.x, k1.x, fmaf(v1.y, k1.y, a11));
            s0 += k0.x + k0.y;
            s1 += k1.x + k1.y;
        }
    }

    float* vp = vk_part + ((size_t)bh * 16 + chunk) * 1056;
    vp[e0 * 32 + d0]            = a00;
    vp[e0 * 32 + d0 + 1]        = a01;
    vp[(e0 + 16) * 32 + d0]     = a10;
    vp[(e0 + 16) * 32 + d0 + 1] = a11;
    if (e0 == 0) {
        vp[32 * 32 + d0]     = s0;
        vp[32 * 32 + d0 + 1] = s1;
    }
}

// Reduce the 16 chunk partials -> vk[bh][33][32]
__global__ __launch_bounds__(256)
void att_vk_reduce(const float* __restrict__ vk_part, float* __restrict__ vk)
{
    const int bh = blockIdx.x;
    const int t  = threadIdx.x;
    for (int id = t; id < 1056; id += 256) {
        const float* p = vk_part + (size_t)bh * 16 * 1056 + id;
        float s = 0;
#pragma unroll
        for (int c = 0; c < 16; c++) s += p[(size_t)c * 1056];
        vk[bh * 1056 + id] = s;
    }
}

// =====================================================================
// M'[b][co][h*32+d] = sum_e w_proj[co][h*32+e] * vk[b*16+h][e][d]  (bf16 out)
// =====================================================================
__global__ __launch_bounds__(256)
void mprep(const float* __restrict__ Wproj, const float* __restrict__ vk,
           unsigned short* __restrict__ Mp)
{
    const int b   = blockIdx.y;
    const int co0 = blockIdx.x * 16;
    const int t   = threadIdx.x;
    for (int ci = 0; ci < 16; ci++) {
        int co = co0 + ci;
        for (int hd = t; hd < 512; hd += 256) {
            int h = hd >> 5, d = hd & 31;
            const float* wrow = Wproj + (size_t)co * 512 + h * 32;
            const float* vkb  = vk + (size_t)(b * 16 + h) * 1056 + d;
            float s = 0;
#pragma unroll
            for (int e = 0; e < 32; e++) s = fmaf(wrow[e], vkb[e * 32], s);
            Mp[((size_t)b * 256 + co) * 512 + hd] = f2b(s);
        }
    }
}

// =====================================================================
// rden[bh][n] = 1 / (sum_d vk[bh][32][d] * relu(q[d][n]) + 1e-15)
// =====================================================================
__global__ __launch_bounds__(256)
void rden_k(const unsigned short* __restrict__ QKVb,
            const unsigned short* __restrict__ AGG2,
            const float* __restrict__ vk, float* __restrict__ Rden)
{
    const int n0 = blockIdx.x * 256;
    const int bh = blockIdx.y;
    const int b = bh >> 4, head = bh & 15;
    const unsigned short* base = (head < 8)
        ? QKVb + ((size_t)b * QKV + head * 96) * Nsp
        : AGG2 + ((size_t)b * QKV + (head - 8) * 96) * Nsp;
    const float* vk1 = vk + (size_t)bh * 1056 + 1024;
    const int t = threadIdx.x;
    float acc = 0;
#pragma unroll
    for (int d = 0; d < 32; d++)
        acc = fmaf(vk1[d], fmaxf(b2f(base[(size_t)d * Nsp + n0 + t]), 0.f), acc);
    Rden[(size_t)bh * Nsp + n0 + t] = 1.0f / (acc + 1e-15f);
}

// =====================================================================
extern "C" void kernel_launch(void* const* d_in, const int* in_sizes, int n_in,
                              void* d_out, int out_size, void* d_ws, size_t ws_size,
                              hipStream_t stream)
{
    const float* x      = (const float*)d_in[0];
    const float* w_qkv  = (const float*)d_in[1];
    const float* w_dw   = (const float*)d_in[2];
    const float* w_pw   = (const float*)d_in[3];
    const float* w_proj = (const float*)d_in[4];
    const float* gamma  = (const float*)d_in[5];
    const float* beta   = (const float*)d_in[6];
    const float* rmean  = (const float*)d_in[7];
    const float* rvar   = (const float*)d_in[8];
    float* out = (float*)d_out;

    const size_t QB = (size_t)2 * QKV * Nsp;        // elements, 2-batch tensor
    unsigned short* qkv  = (unsigned short*)d_ws;   // bf16 [2][768][16384]
    unsigned short* agg2 = qkv + QB;                // bf16 [2][768][16384]
    unsigned short* Rb   = agg2 + QB;               // time-shared 50.3 MB region:
    unsigned short* xT   = Rb;                      //  [2][16384][256]  (steps 2-3)
    unsigned short* aggH = Rb;                      //  [2][768][16384]  (steps 4-5)
    unsigned short* qT   = Rb;                      //  [2][16384][512]  (steps 10-12)
    float* vkp  = (float*)(Rb + QB);                // 32*16*1056
    float* vkf  = vkp + (size_t)32 * 16 * 1056;     // 32*1056
    float* rden = vkf + (size_t)32 * 1056;          // 32*16384 f32
    unsigned short* Mp  = (unsigned short*)(rden + (size_t)32 * 16384); // 2*256*512
    unsigned short* wqb = Mp + (size_t)2 * 256 * 512;                   // 768*256
    // total ~156.3 MB

    dim3 blk(256);
    // 1) w_qkv -> bf16
    cvt_bf16<<<dim3(192), blk, 0, stream>>>(w_qkv, wqb, 768 * 256 / 4);
    // 2) xT = transpose(x) bf16
    transposeT<false><<<dim3(256, 4, 2), blk, 0, stream>>>(
        x, (size_t)256 * Nsp, xT, 256, 0, 32, 0, nullptr);
    // 3) qkv = wqb x xT  (MFMA, bf16 out)
    mfma_gemm<false, true><<<dim3(128, 6, 2), blk, 0, stream>>>(
        wqb, xT, qkv, 256, 768, 0, nullptr, nullptr, nullptr, nullptr);
    // 4) depthwise 5^3, both batches (xT dead)
    dwconv5<<<dim3(768, 2), blk, 0, stream>>>(qkv, w_dw, aggH);
    // 5) grouped pointwise, both batches
    pwconv<<<dim3(64, 24, 2), blk, 0, stream>>>(aggH, w_pw, agg2);
    // 6) vk partials + reduce
    att_vk<<<dim3(16, 32), blk, 0, stream>>>(qkv, agg2, vkp);
    att_vk_reduce<<<dim3(32), blk, 0, stream>>>(vkp, vkf);
    // 7) M' (bf16) and rden
    mprep<<<dim3(16, 2), blk, 0, stream>>>(w_proj, vkf, Mp);
    rden_k<<<dim3(64, 32), blk, 0, stream>>>(qkv, agg2, vkf, rden);
    // 8) q~T = transpose(relu(q)*rden) bf16, both halves (aggH dead)
    transposeT<true><<<dim3(256, 4, 2), blk, 0, stream>>>(
        qkv, (size_t)QKV * Nsp, qT, 512, 0, 96, 0, rden);
    transposeT<true><<<dim3(256, 4, 2), blk, 0, stream>>>(
        agg2, (size_t)QKV * Nsp, qT, 512, 256, 96, 8, rden);
    // 9) out = Mp x q~T + BN  (MFMA, f32 out)
    mfma_gemm<true, false><<<dim3(128, 2, 2), blk, 0, stream>>>(
        Mp, qT, out, 512, 256, (size_t)256 * 512,
        gamma, beta, rmean, rvar);
}